// Round 7
// baseline (312.085 us; speedup 1.0000x reference)
//
#include <hip/hip_runtime.h>
#include <stdint.h>

typedef __attribute__((ext_vector_type(8)))  _Float16 f16x8;
typedef __attribute__((ext_vector_type(4)))  float    f32x4;
typedef __attribute__((ext_vector_type(16))) float    f32x16;

#define M_TOT 8192
#define K_TOT 4096
#define N_TOT 4096
#define KQ    (K_TOT / 8)

#define BM 256
#define BN 256
#define BK 64
#define NWG ((M_TOT / BM) * (N_TOT / BN))   /* 32*16 = 512 */

#define WS_XH_BYTES   ((size_t)M_TOT * K_TOT * 2)
#define WS_WT_BYTES   ((size_t)N_TOT * K_TOT * 2)
#define WS_NEEDED     (WS_XH_BYTES + WS_WT_BYTES)

__device__ __forceinline__ void async_load16(const void* g, void* l) {
    __builtin_amdgcn_global_load_lds(
        (const __attribute__((address_space(1))) void*)g,
        (__attribute__((address_space(3))) void*)l, 16, 0, 0);
}

// ---------------- pre-pass 1: x f32 -> fp16 (exact) --------------------------
__global__ __launch_bounds__(256)
void cvt_x_kernel(const float* __restrict__ x, _Float16* __restrict__ xh) {
    const size_t i = (size_t)(blockIdx.x * 256 + threadIdx.x) * 8;
    f32x4 v0 = *(const f32x4*)(x + i);
    f32x4 v1 = *(const f32x4*)(x + i + 4);
    f16x8 h;
#pragma unroll
    for (int e = 0; e < 4; ++e) { h[e] = (_Float16)v0[e]; h[e + 4] = (_Float16)v1[e]; }
    *(f16x8*)(xh + i) = h;
}

// ---------------- pre-pass 2: dequant qw -> W^T fp16 [n][k] ------------------
__global__ __launch_bounds__(256)
void deq_kernel(const uint32_t* __restrict__ qw, const float* __restrict__ sc,
                const uint32_t* __restrict__ qz, _Float16* __restrict__ wt) {
    const int t  = blockIdx.x * 256 + threadIdx.x;
    const int kq = t & (KQ - 1);
    const int n  = t >> 9;
    const float s = sc[n];
    const uint32_t z4 = (qz[n >> 3] >> ((n & 7) * 4)) & 15u;
    const float zoff = (float)(z4 + 1u) * s;
    const uint32_t q = qw[(size_t)kq * N_TOT + n];
    f16x8 w;
#pragma unroll
    for (int e = 0; e < 8; ++e)
        w[e] = (_Float16)fmaf((float)((q >> (4 * e)) & 15u), s, -zoff);
    *(f16x8*)(wt + (size_t)n * K_TOT + kq * 8) = w;
}

// ---------------- main GEMM: 256x256, 8-phase, 32x32x16 MFMA, snake order ----
// Regions per buf: 0=A rows0-127, 1=A rows128-255, 2=B cols0-127, 3=B cols128-255.
// Per tile: P1 reads A(mh0)+B(nh0), P2 B(nh1), P3 A(mh1), P4 none (regs reused).
// Region last-read: B->P2, A->P3. Stage slots: P1:t+1.R1 P2:t+1.R2 P3:t+1.R3
// P4:t+2.R0 (then P5-P7: t+2.R1-R3, P8: t+3.R0). VM(2) at P4/P8 drains all but
// the newest stage -> next tile's 4 regions proven landed; never vmcnt(0).
__global__ __launch_bounds__(512, 2)
void gemm8p_kernel(const _Float16* __restrict__ xh,   // (M,K) fp16
                   const _Float16* __restrict__ wt,   // (N,K) fp16
                   const float* __restrict__ bias,    // (N) f32
                   float* __restrict__ out)           // (M,N) f32
{
    __shared__ __align__(16) _Float16 lds[2 * 4 * 8192];   // 128 KiB

    const int tid  = threadIdx.x;
    const int lane = tid & 63;
    const int wave = tid >> 6;
    const int wm = wave >> 2;          // 0..1  A region / 128-row half
    const int wn = wave & 3;           // 0..3  64-col quarter
    const int l31 = lane & 31;
    const int lhi = lane >> 5;         // k-chunk select within kstep

    const int bid = blockIdx.x;
    const int swz = (bid & 7) * (NWG / 8) + (bid >> 3);   // bijective, 512%8==0
    const int m0 = (swz >> 4) * BM;
    const int n0 = (swz & 15) * BN;

    // staging geometry (unchanged): region = 128 rows x 64 k, linear LDS dest,
    // pre-swizzled global source chunk
    const int srow = tid >> 3;
    const int c_g  = (tid & 7) ^ (srow & 7);
    const _Float16* gA[2]; const _Float16* gB[2];
    gA[0] = xh + (size_t)(m0 + srow) * K_TOT + c_g * 8;
    gA[1] = xh + (size_t)(m0 + 128 + srow) * K_TOT + c_g * 8;
    gB[0] = wt + (size_t)(n0 + srow) * K_TOT + c_g * 8;
    gB[1] = wt + (size_t)(n0 + 128 + srow) * K_TOT + c_g * 8;

#define STAGE(tile, r) do {                                                    \
    const _Float16* _s = ((r) < 2 ? gA[(r)] : gB[(r) - 2]) + (size_t)(tile) * BK; \
    _Float16* _d = lds + (((tile) & 1) * 4 + (r)) * 8192 + tid * 8;            \
    async_load16(_s, _d);                                                      \
    async_load16(_s + (size_t)64 * K_TOT, _d + 4096);                          \
} while (0)

// A frags for half mh: rowblks {2mh, 2mh+1}, 4 ksteps each -> afr[rbl*4+s]
#define LDA(buf, mh) do {                                                      \
    const _Float16* _b = lds + ((buf) * 4 + wm) * 8192;                        \
    _Pragma("unroll") for (int _rbl = 0; _rbl < 2; ++_rbl) {                   \
        const int _row = (mh) * 64 + _rbl * 32 + l31;                          \
        _Pragma("unroll") for (int _s = 0; _s < 4; ++_s) {                     \
            const int _cp = (_s * 2 + lhi) ^ (_row & 7);                       \
            afr[_rbl * 4 + _s] = *(const f16x8*)(_b + _row * 64 + _cp * 8);    \
        }                                                                      \
    }                                                                          \
} while (0)

// B frags for col-block nh (32 cols), 4 ksteps -> dst[s]
#define LDB(buf, nh, dst) do {                                                 \
    const _Float16* _b = lds + ((buf) * 4 + 2 + (wn >> 1)) * 8192;             \
    const int _row = (wn & 1) * 64 + (nh) * 32 + l31;                          \
    _Pragma("unroll") for (int _s = 0; _s < 4; ++_s) {                         \
        const int _cp = (_s * 2 + lhi) ^ (_row & 7);                           \
        dst[_s] = *(const f16x8*)(_b + _row * 64 + _cp * 8);                   \
    }                                                                          \
} while (0)

#define MFMAQ(mh, nh, bsrc) do {                                               \
    __builtin_amdgcn_s_setprio(1);                                             \
    _Pragma("unroll") for (int _rbl = 0; _rbl < 2; ++_rbl)                     \
    _Pragma("unroll") for (int _s = 0; _s < 4; ++_s)                           \
        acc[((mh) * 2 + _rbl) * 2 + (nh)] =                                    \
            __builtin_amdgcn_mfma_f32_32x32x16_f16(                            \
                afr[_rbl * 4 + _s], bsrc[_s],                                  \
                acc[((mh) * 2 + _rbl) * 2 + (nh)], 0, 0, 0);                   \
    __builtin_amdgcn_s_setprio(0);                                             \
} while (0)

#define SB() do { asm volatile("" ::: "memory");                               \
    __builtin_amdgcn_s_barrier(); asm volatile("" ::: "memory"); } while (0)
#define VM(n) asm volatile("s_waitcnt vmcnt(" #n ")" ::: "memory")

    f32x16 acc[8];   // [rowblk(4) * 2 + colblk(2)]
#pragma unroll
    for (int t = 0; t < 8; ++t)
#pragma unroll
        for (int r = 0; r < 16; ++r)
            acc[t][r] = 0.f;

    f16x8 afr[8], bfr0[4], bfr1[4];

    // prologue: tile0 complete + tile1.A_lo in flight
    STAGE(0, 0); STAGE(0, 1); STAGE(0, 2); STAGE(0, 3);
    STAGE(1, 0);
    VM(2); SB();

    for (int i = 0; i < 31; ++i) {
        const int t0 = 2 * i;
        // tile t0 (buf0)
        LDA(0, 0); LDB(0, 0, bfr0); STAGE(t0 + 1, 1); SB(); MFMAQ(0, 0, bfr0); SB();
        LDB(0, 1, bfr1);            STAGE(t0 + 1, 2); SB(); MFMAQ(0, 1, bfr1); SB();
        LDA(0, 1);                  STAGE(t0 + 1, 3); SB(); MFMAQ(1, 1, bfr1); SB();
                                    STAGE(t0 + 2, 0); SB(); MFMAQ(1, 0, bfr0); VM(2); SB();
        // tile t0+1 (buf1)
        LDA(1, 0); LDB(1, 0, bfr0); STAGE(t0 + 2, 1); SB(); MFMAQ(0, 0, bfr0); SB();
        LDB(1, 1, bfr1);            STAGE(t0 + 2, 2); SB(); MFMAQ(0, 1, bfr1); SB();
        LDA(1, 1);                  STAGE(t0 + 2, 3); SB(); MFMAQ(1, 1, bfr1); SB();
                                    STAGE(t0 + 3, 0); SB(); MFMAQ(1, 0, bfr0); VM(2); SB();
    }
    // tail: tiles 62 (buf0), 63 (buf1); no stages past 63
    LDA(0, 0); LDB(0, 0, bfr0); STAGE(63, 1); SB(); MFMAQ(0, 0, bfr0); SB();
    LDB(0, 1, bfr1);            STAGE(63, 2); SB(); MFMAQ(0, 1, bfr1); SB();
    LDA(0, 1);                  STAGE(63, 3); SB(); MFMAQ(1, 1, bfr1); SB();
                                              SB(); MFMAQ(1, 0, bfr0); VM(0); SB();
    LDA(1, 0); LDB(1, 0, bfr0);               SB(); MFMAQ(0, 0, bfr0); SB();
    LDB(1, 1, bfr1);                          SB(); MFMAQ(0, 1, bfr1); SB();
    LDA(1, 1);                                SB(); MFMAQ(1, 1, bfr1); SB();
                                              SB(); MFMAQ(1, 0, bfr0); SB();

    // epilogue: ref semantics y=fp16(acc); out=f32(fp16(y + fp16(bias)))
    // 32x32 C/D: col = lane&31, row = (r&3) + 8*(r>>2) + 4*(lane>>5)
#pragma unroll
    for (int cb = 0; cb < 2; ++cb) {
        const int col = n0 + wn * 64 + cb * 32 + l31;
        const _Float16 bh = (_Float16)bias[col];
#pragma unroll
        for (int rb = 0; rb < 4; ++rb) {
            const int rbase = m0 + wm * 128 + rb * 32 + 4 * lhi;
#pragma unroll
            for (int r = 0; r < 16; ++r) {
                const int grow = rbase + (r & 3) + 8 * (r >> 2);
                const _Float16 y = (_Float16)acc[rb * 2 + cb][r];
                out[(size_t)grow * N_TOT + col] = (float)(_Float16)(y + bh);
            }
        }
    }
#undef STAGE
#undef LDA
#undef LDB
#undef MFMAQ
#undef SB
#undef VM
}

// ---------------- fallback (proven correct, slow) ----------------------------
__global__ __launch_bounds__(256)
void qlinf32_kernel(const float* __restrict__ x, const uint32_t* __restrict__ qw,
                    const float* __restrict__ sc, const uint32_t* __restrict__ qz,
                    const float* __restrict__ bias, float* __restrict__ out)
{
    const int idx = blockIdx.x * 256 + threadIdx.x;
    const int n   = idx & (N_TOT - 1);
    const int mb  = (idx >> 12) << 2;
    const float s = sc[n];
    const uint32_t z4 = (qz[n >> 3] >> ((n & 7) * 4)) & 15u;
    const float zoff = (float)(z4 + 1u) * s;
    float acc[4] = {0.f, 0.f, 0.f, 0.f};
    const float* xr = x + (size_t)mb * K_TOT;
    for (int kq = 0; kq < KQ; ++kq) {
        const uint32_t q = qw[(size_t)kq * N_TOT + n];
        f32x4 xa[4][2];
#pragma unroll
        for (int r = 0; r < 4; ++r) {
            xa[r][0] = *(const f32x4*)(xr + r * K_TOT + kq * 8);
            xa[r][1] = *(const f32x4*)(xr + r * K_TOT + kq * 8 + 4);
        }
#pragma unroll
        for (int e = 0; e < 8; ++e) {
            const float w = fmaf((float)((q >> (4 * e)) & 15u), s, -zoff);
#pragma unroll
            for (int r = 0; r < 4; ++r)
                acc[r] = fmaf(xa[r][e >> 2][e & 3], w, acc[r]);
        }
    }
    const _Float16 bh = (_Float16)bias[n];
#pragma unroll
    for (int r = 0; r < 4; ++r) {
        _Float16 y = (_Float16)acc[r];
        out[(size_t)(mb + r) * N_TOT + n] = (float)(_Float16)(y + bh);
    }
}

extern "C" void kernel_launch(void* const* d_in, const int* in_sizes, int n_in,
                              void* d_out, int out_size, void* d_ws, size_t ws_size,
                              hipStream_t stream) {
    int ix = -1, iqw = -1, iqz = -1, isc = -1, ibi = -1;
    for (int i = 0; i < n_in; ++i) {
        const int sz = in_sizes[i];
        if      (sz == 33554432) ix  = i;
        else if (sz == 2097152)  iqw = i;
        else if (sz == 512)      iqz = i;
        else if (sz == 4096)     { if (isc < 0) isc = i; else ibi = i; }
    }
    if (ix < 0)  ix = 0;
    if (iqw < 0) iqw = 1;
    if (isc < 0) isc = 2;
    if (iqz < 0) iqz = 3;
    if (ibi < 0) ibi = 4;

    const float*    xv = (const float*)d_in[ix];
    const uint32_t* qw = (const uint32_t*)d_in[iqw];
    const float*    sc = (const float*)d_in[isc];
    const uint32_t* qz = (const uint32_t*)d_in[iqz];
    const float*    bi = (const float*)d_in[ibi];
    float*         out = (float*)d_out;

    if (ws_size < WS_NEEDED) {
        const int blocks = (M_TOT / 4) * N_TOT / 256;
        hipLaunchKernelGGL(qlinf32_kernel, dim3(blocks), dim3(256), 0, stream,
                           xv, qw, sc, qz, bi, out);
        return;
    }

    _Float16* xh = (_Float16*)d_ws;
    _Float16* wt = (_Float16*)((char*)d_ws + WS_XH_BYTES);

    hipLaunchKernelGGL(cvt_x_kernel, dim3(M_TOT * K_TOT / 8 / 256), dim3(256),
                       0, stream, xv, xh);
    hipLaunchKernelGGL(deq_kernel, dim3(KQ * N_TOT / 256), dim3(256),
                       0, stream, qw, sc, qz, wt);
    hipLaunchKernelGGL(gemm8p_kernel, dim3(NWG), dim3(512), 0, stream,
                       xh, wt, bi, out);
}

// Round 8
// 282.013 us; speedup vs baseline: 1.1066x; 1.1066x over previous
//
#include <hip/hip_runtime.h>
#include <stdint.h>

typedef __attribute__((ext_vector_type(8))) _Float16 f16x8;
typedef __attribute__((ext_vector_type(4))) float f32x4;

#define M_TOT 8192
#define K_TOT 4096
#define N_TOT 4096
#define KQ    (K_TOT / 8)

#define BM 256
#define BN 256
#define BK 64
#define NWG ((M_TOT / BM) * (N_TOT / BN))   /* 32*16 = 512 */

#define WS_XH_BYTES   ((size_t)M_TOT * K_TOT * 2)
#define WS_WT_BYTES   ((size_t)N_TOT * K_TOT * 2)
#define WS_NEEDED     (WS_XH_BYTES + WS_WT_BYTES)

__device__ __forceinline__ void async_load16(const void* g, void* l) {
    __builtin_amdgcn_global_load_lds(
        (const __attribute__((address_space(1))) void*)g,
        (__attribute__((address_space(3))) void*)l, 16, 0, 0);
}

// ---------------- pre-pass 1: x f32 -> fp16 (exact) --------------------------
__global__ __launch_bounds__(256)
void cvt_x_kernel(const float* __restrict__ x, _Float16* __restrict__ xh) {
    const size_t i = (size_t)(blockIdx.x * 256 + threadIdx.x) * 8;
    f32x4 v0 = *(const f32x4*)(x + i);
    f32x4 v1 = *(const f32x4*)(x + i + 4);
    f16x8 h;
#pragma unroll
    for (int e = 0; e < 4; ++e) { h[e] = (_Float16)v0[e]; h[e + 4] = (_Float16)v1[e]; }
    *(f16x8*)(xh + i) = h;
}

// ---------------- pre-pass 2: dequant qw -> W^T fp16 [n][k] ------------------
__global__ __launch_bounds__(256)
void deq_kernel(const uint32_t* __restrict__ qw, const float* __restrict__ sc,
                const uint32_t* __restrict__ qz, _Float16* __restrict__ wt) {
    const int t  = blockIdx.x * 256 + threadIdx.x;
    const int kq = t & (KQ - 1);
    const int n  = t >> 9;
    const float s = sc[n];
    const uint32_t z4 = (qz[n >> 3] >> ((n & 7) * 4)) & 15u;
    const float zoff = (float)(z4 + 1u) * s;
    const uint32_t q = qw[(size_t)kq * N_TOT + n];
    f16x8 w;
#pragma unroll
    for (int e = 0; e < 8; ++e)
        w[e] = (_Float16)fmaf((float)((q >> (4 * e)) & 15u), s, -zoff);
    *(f16x8*)(wt + (size_t)n * K_TOT + kq * 8) = w;
}

// ---------------- main GEMM: 256x256, 8-phase, 16x16x32 MFMA, snake order ----
// Regions per buf: 0=A rows0-127, 1=A rows128-255, 2=B cols0-127, 3=B cols128-255.
// Snake per tile: P1 (mh0,nh0) reads LDA+LDB0; P2 (mh0,nh1) reads LDB1;
// P3 (mh1,nh1) reads LDA; P4 (mh1,nh0) reads nothing (bfr0/afr persist).
// Region last-read: A->P3, B->P2. Stage slots: P1:t+1.R1 P2:t+1.R2 P3:t+1.R3
// P4:t+2.R0. VM(2) at P4/P8 leaves only the newest stage in flight -> next
// tile's 4 regions proven landed; never vmcnt(0) in the main loop.
__global__ __launch_bounds__(512, 2)
void gemm8p_kernel(const _Float16* __restrict__ xh,   // (M,K) fp16
                   const _Float16* __restrict__ wt,   // (N,K) fp16
                   const float* __restrict__ bias,    // (N) f32
                   float* __restrict__ out)           // (M,N) f32
{
    __shared__ __align__(16) _Float16 lds[2 * 4 * 8192];   // 128 KiB

    const int tid  = threadIdx.x;
    const int lane = tid & 63;
    const int wave = tid >> 6;
    const int wm = wave >> 2;          // 0..1  A region / 128-row half
    const int wn = wave & 3;           // 0..3  64-col quarter
    const int fr = lane & 15;
    const int fk = lane >> 4;

    const int bid = blockIdx.x;
    const int swz = (bid & 7) * (NWG / 8) + (bid >> 3);   // bijective, 512%8==0
    const int m0 = (swz >> 4) * BM;
    const int n0 = (swz & 15) * BN;

    // staging geometry: region = 128 rows x 64 k, linear LDS dest,
    // pre-swizzled global source chunk (proven 0-conflict in R6)
    const int srow = tid >> 3;
    const int c_g  = (tid & 7) ^ (srow & 7);
    const _Float16* gA[2]; const _Float16* gB[2];
    gA[0] = xh + (size_t)(m0 + srow) * K_TOT + c_g * 8;
    gA[1] = xh + (size_t)(m0 + 128 + srow) * K_TOT + c_g * 8;
    gB[0] = wt + (size_t)(n0 + srow) * K_TOT + c_g * 8;
    gB[1] = wt + (size_t)(n0 + 128 + srow) * K_TOT + c_g * 8;

#define STAGE(tile, r) do {                                                    \
    const _Float16* _s = ((r) < 2 ? gA[(r)] : gB[(r) - 2]) + (size_t)(tile) * BK; \
    _Float16* _d = lds + (((tile) & 1) * 4 + (r)) * 8192 + tid * 8;            \
    async_load16(_s, _d);                                                      \
    async_load16(_s + (size_t)64 * K_TOT, _d + 4096);                          \
} while (0)

// A frags, row-half mh of this wave's region: rows (mh*4+mf)*16+fr  [R6 exact]
#define LDA(buf, mh) do {                                                      \
    const _Float16* _b = lds + ((buf) * 4 + wm) * 8192;                        \
    _Pragma("unroll") for (int _mf = 0; _mf < 4; ++_mf) {                      \
        const int _row = ((mh) * 4 + _mf) * 16 + fr;                           \
        _Pragma("unroll") for (int _kk = 0; _kk < 2; ++_kk) {                  \
            const int _cp = ((_kk << 2) | fk) ^ (_row & 7);                    \
            afr[_mf * 2 + _kk] = *(const f16x8*)(_b + _row * 64 + _cp * 8);    \
        }                                                                      \
    }                                                                          \
} while (0)

// B frags, 32-col block nh of this wave's 64 cols  [R6 exact]
#define LDB(buf, nh, dst) do {                                                 \
    const _Float16* _b = lds + ((buf) * 4 + 2 + (wn >> 1)) * 8192;             \
    _Pragma("unroll") for (int _nf = 0; _nf < 2; ++_nf) {                      \
        const int _row = (wn & 1) * 64 + ((nh) * 2 + _nf) * 16 + fr;           \
        _Pragma("unroll") for (int _kk = 0; _kk < 2; ++_kk) {                  \
            const int _cp = ((_kk << 2) | fk) ^ (_row & 7);                    \
            dst[_nf * 2 + _kk] = *(const f16x8*)(_b + _row * 64 + _cp * 8);    \
        }                                                                      \
    }                                                                          \
} while (0)

#define MFMAQ(mh, nh, bsrc) do {                                               \
    __builtin_amdgcn_s_setprio(1);                                             \
    _Pragma("unroll") for (int _mf = 0; _mf < 4; ++_mf)                        \
    _Pragma("unroll") for (int _nf = 0; _nf < 2; ++_nf)                        \
    _Pragma("unroll") for (int _kk = 0; _kk < 2; ++_kk)                        \
        acc[(mh) * 4 + _mf][(nh) * 2 + _nf] =                                  \
            __builtin_amdgcn_mfma_f32_16x16x32_f16(                            \
                afr[_mf * 2 + _kk], bsrc[_nf * 2 + _kk],                       \
                acc[(mh) * 4 + _mf][(nh) * 2 + _nf], 0, 0, 0);                 \
    __builtin_amdgcn_s_setprio(0);                                             \
} while (0)

#define SB() do { asm volatile("" ::: "memory");                               \
    __builtin_amdgcn_s_barrier(); asm volatile("" ::: "memory"); } while (0)
#define VM(n) asm volatile("s_waitcnt vmcnt(" #n ")" ::: "memory")

    f32x4 acc[8][4];
#pragma unroll
    for (int m = 0; m < 8; ++m)
#pragma unroll
        for (int n = 0; n < 4; ++n)
            acc[m][n] = (f32x4){0.f, 0.f, 0.f, 0.f};

    f16x8 afr[8], bfr0[4], bfr1[4];

    // prologue: tile0 complete + tile1.R0 in flight
    STAGE(0, 0); STAGE(0, 1); STAGE(0, 2); STAGE(0, 3);
    STAGE(1, 0);
    VM(2); SB();

    for (int i = 0; i < 31; ++i) {
        const int t0 = 2 * i;
        // tile t0 (buf0): snake (0,0)->(0,1)->(1,1)->(1,0)
        LDA(0, 0); LDB(0, 0, bfr0); STAGE(t0 + 1, 1); SB(); MFMAQ(0, 0, bfr0); SB();
        LDB(0, 1, bfr1);            STAGE(t0 + 1, 2); SB(); MFMAQ(0, 1, bfr1); SB();
        LDA(0, 1);                  STAGE(t0 + 1, 3); SB(); MFMAQ(1, 1, bfr1); SB();
                                    STAGE(t0 + 2, 0); SB(); MFMAQ(1, 0, bfr0); VM(2); SB();
        // tile t0+1 (buf1)
        LDA(1, 0); LDB(1, 0, bfr0); STAGE(t0 + 2, 1); SB(); MFMAQ(0, 0, bfr0); SB();
        LDB(1, 1, bfr1);            STAGE(t0 + 2, 2); SB(); MFMAQ(0, 1, bfr1); SB();
        LDA(1, 1);                  STAGE(t0 + 2, 3); SB(); MFMAQ(1, 1, bfr1); SB();
                                    STAGE(t0 + 3, 0); SB(); MFMAQ(1, 0, bfr0); VM(2); SB();
    }
    // tail: tiles 62 (buf0), 63 (buf1); no stages past 63
    LDA(0, 0); LDB(0, 0, bfr0); STAGE(63, 1); SB(); MFMAQ(0, 0, bfr0); SB();
    LDB(0, 1, bfr1);            STAGE(63, 2); SB(); MFMAQ(0, 1, bfr1); SB();
    LDA(0, 1);                  STAGE(63, 3); SB(); MFMAQ(1, 1, bfr1); SB();
                                              SB(); MFMAQ(1, 0, bfr0); VM(0); SB();
    LDA(1, 0); LDB(1, 0, bfr0);               SB(); MFMAQ(0, 0, bfr0); SB();
    LDB(1, 1, bfr1);                          SB(); MFMAQ(0, 1, bfr1); SB();
    LDA(1, 1);                                SB(); MFMAQ(1, 1, bfr1); SB();
                                              SB(); MFMAQ(1, 0, bfr0); SB();

    // epilogue: ref semantics y=fp16(acc); out=f32(fp16(y + fp16(bias)))
#pragma unroll
    for (int nf = 0; nf < 4; ++nf) {
        const int col = n0 + wn * 64 + nf * 16 + fr;
        const _Float16 bh = (_Float16)bias[col];
#pragma unroll
        for (int mf = 0; mf < 8; ++mf) {
            const int row0 = m0 + wm * 128 + mf * 16 + fk * 4;
#pragma unroll
            for (int r = 0; r < 4; ++r) {
                const _Float16 y = (_Float16)acc[mf][nf][r];
                out[(size_t)(row0 + r) * N_TOT + col] = (float)(_Float16)(y + bh);
            }
        }
    }
#undef STAGE
#undef LDA
#undef LDB
#undef MFMAQ
#undef SB
#undef VM
}

// ---------------- fallback (proven correct, slow) ----------------------------
__global__ __launch_bounds__(256)
void qlinf32_kernel(const float* __restrict__ x, const uint32_t* __restrict__ qw,
                    const float* __restrict__ sc, const uint32_t* __restrict__ qz,
                    const float* __restrict__ bias, float* __restrict__ out)
{
    const int idx = blockIdx.x * 256 + threadIdx.x;
    const int n   = idx & (N_TOT - 1);
    const int mb  = (idx >> 12) << 2;
    const float s = sc[n];
    const uint32_t z4 = (qz[n >> 3] >> ((n & 7) * 4)) & 15u;
    const float zoff = (float)(z4 + 1u) * s;
    float acc[4] = {0.f, 0.f, 0.f, 0.f};
    const float* xr = x + (size_t)mb * K_TOT;
    for (int kq = 0; kq < KQ; ++kq) {
        const uint32_t q = qw[(size_t)kq * N_TOT + n];
        f32x4 xa[4][2];
#pragma unroll
        for (int r = 0; r < 4; ++r) {
            xa[r][0] = *(const f32x4*)(xr + r * K_TOT + kq * 8);
            xa[r][1] = *(const f32x4*)(xr + r * K_TOT + kq * 8 + 4);
        }
#pragma unroll
        for (int e = 0; e < 8; ++e) {
            const float w = fmaf((float)((q >> (4 * e)) & 15u), s, -zoff);
#pragma unroll
            for (int r = 0; r < 4; ++r)
                acc[r] = fmaf(xa[r][e >> 2][e & 3], w, acc[r]);
        }
    }
    const _Float16 bh = (_Float16)bias[n];
#pragma unroll
    for (int r = 0; r < 4; ++r) {
        _Float16 y = (_Float16)acc[r];
        out[(size_t)(mb + r) * N_TOT + n] = (float)(_Float16)(y + bh);
    }
}

extern "C" void kernel_launch(void* const* d_in, const int* in_sizes, int n_in,
                              void* d_out, int out_size, void* d_ws, size_t ws_size,
                              hipStream_t stream) {
    int ix = -1, iqw = -1, iqz = -1, isc = -1, ibi = -1;
    for (int i = 0; i < n_in; ++i) {
        const int sz = in_sizes[i];
        if      (sz == 33554432) ix  = i;
        else if (sz == 2097152)  iqw = i;
        else if (sz == 512)      iqz = i;
        else if (sz == 4096)     { if (isc < 0) isc = i; else ibi = i; }
    }
    if (ix < 0)  ix = 0;
    if (iqw < 0) iqw = 1;
    if (isc < 0) isc = 2;
    if (iqz < 0) iqz = 3;
    if (ibi < 0) ibi = 4;

    const float*    xv = (const float*)d_in[ix];
    const uint32_t* qw = (const uint32_t*)d_in[iqw];
    const float*    sc = (const float*)d_in[isc];
    const uint32_t* qz = (const uint32_t*)d_in[iqz];
    const float*    bi = (const float*)d_in[ibi];
    float*         out = (float*)d_out;

    if (ws_size < WS_NEEDED) {
        const int blocks = (M_TOT / 4) * N_TOT / 256;
        hipLaunchKernelGGL(qlinf32_kernel, dim3(blocks), dim3(256), 0, stream,
                           xv, qw, sc, qz, bi, out);
        return;
    }

    _Float16* xh = (_Float16*)d_ws;
    _Float16* wt = (_Float16*)((char*)d_ws + WS_XH_BYTES);

    hipLaunchKernelGGL(cvt_x_kernel, dim3(M_TOT * K_TOT / 8 / 256), dim3(256),
                       0, stream, xv, xh);
    hipLaunchKernelGGL(deq_kernel, dim3(KQ * N_TOT / 256), dim3(256),
                       0, stream, qw, sc, qz, wt);
    hipLaunchKernelGGL(gemm8p_kernel, dim3(NWG), dim3(512), 0, stream,
                       xh, wt, bi, out);
}

// Round 9
// 280.677 us; speedup vs baseline: 1.1119x; 1.0048x over previous
//
#include <hip/hip_runtime.h>
#include <stdint.h>

typedef __attribute__((ext_vector_type(8))) _Float16 f16x8;
typedef __attribute__((ext_vector_type(4))) float f32x4;

#define M_TOT 8192
#define K_TOT 4096
#define N_TOT 4096
#define KQ    (K_TOT / 8)

#define BM 256
#define BN 256
#define BK 64
#define NWG ((M_TOT / BM) * (N_TOT / BN))   /* 32*16 = 512 */

#define WS_XH_BYTES   ((size_t)M_TOT * K_TOT * 2)
#define WS_WT_BYTES   ((size_t)N_TOT * K_TOT * 2)
#define WS_NEEDED     (WS_XH_BYTES + WS_WT_BYTES)

__device__ __forceinline__ void async_load16(const void* g, void* l) {
    __builtin_amdgcn_global_load_lds(
        (const __attribute__((address_space(1))) void*)g,
        (__attribute__((address_space(3))) void*)l, 16, 0, 0);
}

// ---------------- pre-pass 1: x f32 -> fp16 (exact) --------------------------
__global__ __launch_bounds__(256)
void cvt_x_kernel(const float* __restrict__ x, _Float16* __restrict__ xh) {
    const size_t i = (size_t)(blockIdx.x * 256 + threadIdx.x) * 8;
    f32x4 v0 = *(const f32x4*)(x + i);
    f32x4 v1 = *(const f32x4*)(x + i + 4);
    f16x8 h;
#pragma unroll
    for (int e = 0; e < 4; ++e) { h[e] = (_Float16)v0[e]; h[e + 4] = (_Float16)v1[e]; }
    *(f16x8*)(xh + i) = h;
}

// ---------------- pre-pass 2: dequant qw -> W^T fp16 [n][k] ------------------
__global__ __launch_bounds__(256)
void deq_kernel(const uint32_t* __restrict__ qw, const float* __restrict__ sc,
                const uint32_t* __restrict__ qz, _Float16* __restrict__ wt) {
    const int t  = blockIdx.x * 256 + threadIdx.x;
    const int kq = t & (KQ - 1);
    const int n  = t >> 9;
    const float s = sc[n];
    const uint32_t z4 = (qz[n >> 3] >> ((n & 7) * 4)) & 15u;
    const float zoff = (float)(z4 + 1u) * s;
    const uint32_t q = qw[(size_t)kq * N_TOT + n];
    f16x8 w;
#pragma unroll
    for (int e = 0; e < 8; ++e)
        w[e] = (_Float16)fmaf((float)((q >> (4 * e)) & 15u), s, -zoff);
    *(f16x8*)(wt + (size_t)n * K_TOT + kq * 8) = w;
}

// ---------------- main GEMM: 256x256, 8-phase, hidden-read schedule ----------
// Regions/buf: 0=A rows0-127, 1=A rows128-255, 2=B cols0-127, 3=B cols128-255.
// Snake: Q1=(0,0) Q2=(0,1) Q3=(1,1) Q4=(1,0).
// Read schedule (register-neutral hiding):
//   P1 pre : bfr0+afrL (12, consumption-ordered -> fine-grained lgkm pipelines)
//   P1 post: bfr1 (4)   [old bfr1 dead since prev Q3; hidden under Q1+barriers]
//   P2 post: afrH (8)   [afr(mh0) dead after Q2's MFMA; hidden under barriers]
//   P3/P4  : no reads.
// Stage slots: P1:t+1.R1 P2:t+1.R2 P3:t+1.R3 P4:t+2.R0. VM(2) at P4 leaves only
// P4's own stage in flight -> all 4 regions of t+1 landed before next P1 reads.
// All post-MFMA reads precede a barrier; all consumers are >=1 barrier later.
__global__ __launch_bounds__(512, 2)
void gemm8p_kernel(const _Float16* __restrict__ xh,   // (M,K) fp16
                   const _Float16* __restrict__ wt,   // (N,K) fp16
                   const float* __restrict__ bias,    // (N) f32
                   float* __restrict__ out)           // (M,N) f32
{
    __shared__ __align__(16) _Float16 lds[2 * 4 * 8192];   // 128 KiB

    const int tid  = threadIdx.x;
    const int lane = tid & 63;
    const int wave = tid >> 6;
    const int wm = wave >> 2;          // 0..1  A region / 128-row half
    const int wn = wave & 3;           // 0..3  64-col quarter
    const int fr = lane & 15;
    const int fk = lane >> 4;

    const int bid = blockIdx.x;
    const int swz = (bid & 7) * (NWG / 8) + (bid >> 3);   // bijective, 512%8==0
    const int m0 = (swz >> 4) * BM;
    const int n0 = (swz & 15) * BN;

    const int srow = tid >> 3;
    const int c_g  = (tid & 7) ^ (srow & 7);
    const _Float16* gA[2]; const _Float16* gB[2];
    gA[0] = xh + (size_t)(m0 + srow) * K_TOT + c_g * 8;
    gA[1] = xh + (size_t)(m0 + 128 + srow) * K_TOT + c_g * 8;
    gB[0] = wt + (size_t)(n0 + srow) * K_TOT + c_g * 8;
    gB[1] = wt + (size_t)(n0 + 128 + srow) * K_TOT + c_g * 8;

#define STAGE(tile, r) do {                                                    \
    const _Float16* _s = ((r) < 2 ? gA[(r)] : gB[(r) - 2]) + (size_t)(tile) * BK; \
    _Float16* _d = lds + (((tile) & 1) * 4 + (r)) * 8192 + tid * 8;            \
    async_load16(_s, _d);                                                      \
    async_load16(_s + (size_t)64 * K_TOT, _d + 4096);                          \
} while (0)

// one A frag (row-half mh, frag mf, kslice kk) -> afr[mf*2+kk]
#define LD_A1(buf, mh, _mf, _kk) do {                                          \
    const _Float16* _b = lds + ((buf) * 4 + wm) * 8192;                        \
    const int _row = ((mh) * 4 + (_mf)) * 16 + fr;                             \
    const int _cp = (((_kk) << 2) | fk) ^ (_row & 7);                          \
    afr[(_mf) * 2 + (_kk)] = *(const f16x8*)(_b + _row * 64 + _cp * 8);        \
} while (0)

// one B frag (col-block nh, frag nf, kslice kk) -> dst[nf*2+kk]
#define LD_B1(buf, nh, _nf, _kk, dst) do {                                     \
    const _Float16* _b = lds + ((buf) * 4 + 2 + (wn >> 1)) * 8192;             \
    const int _row = (wn & 1) * 64 + ((nh) * 2 + (_nf)) * 16 + fr;             \
    const int _cp = (((_kk) << 2) | fk) ^ (_row & 7);                          \
    dst[(_nf) * 2 + (_kk)] = *(const f16x8*)(_b + _row * 64 + _cp * 8);        \
} while (0)

// P1 pre-barrier reads, MFMA-consumption-ordered: b0,b1,a0,a1,b2,b3,a2..a7
#define LD_P1(buf) do {                                                        \
    LD_B1(buf, 0, 0, 0, bfr0); LD_B1(buf, 0, 0, 1, bfr0);                      \
    LD_A1(buf, 0, 0, 0);       LD_A1(buf, 0, 0, 1);                            \
    LD_B1(buf, 0, 1, 0, bfr0); LD_B1(buf, 0, 1, 1, bfr0);                      \
    LD_A1(buf, 0, 1, 0);       LD_A1(buf, 0, 1, 1);                            \
    LD_A1(buf, 0, 2, 0);       LD_A1(buf, 0, 2, 1);                            \
    LD_A1(buf, 0, 3, 0);       LD_A1(buf, 0, 3, 1);                            \
} while (0)

#define LD_BFR1(buf) do {                                                      \
    LD_B1(buf, 1, 0, 0, bfr1); LD_B1(buf, 1, 0, 1, bfr1);                      \
    LD_B1(buf, 1, 1, 0, bfr1); LD_B1(buf, 1, 1, 1, bfr1);                      \
} while (0)

#define LD_AFRH(buf) do {                                                      \
    LD_A1(buf, 1, 0, 0); LD_A1(buf, 1, 0, 1);                                  \
    LD_A1(buf, 1, 1, 0); LD_A1(buf, 1, 1, 1);                                  \
    LD_A1(buf, 1, 2, 0); LD_A1(buf, 1, 2, 1);                                  \
    LD_A1(buf, 1, 3, 0); LD_A1(buf, 1, 3, 1);                                  \
} while (0)

#define MFMAQ(mh, nh, bsrc) do {                                               \
    __builtin_amdgcn_s_setprio(1);                                             \
    _Pragma("unroll") for (int _mf = 0; _mf < 4; ++_mf)                        \
    _Pragma("unroll") for (int _nf = 0; _nf < 2; ++_nf)                        \
    _Pragma("unroll") for (int _kk = 0; _kk < 2; ++_kk)                        \
        acc[(mh) * 4 + _mf][(nh) * 2 + _nf] =                                  \
            __builtin_amdgcn_mfma_f32_16x16x32_f16(                            \
                afr[_mf * 2 + _kk], bsrc[_nf * 2 + _kk],                       \
                acc[(mh) * 4 + _mf][(nh) * 2 + _nf], 0, 0, 0);                 \
    __builtin_amdgcn_s_setprio(0);                                             \
} while (0)

#define SB() do { asm volatile("" ::: "memory");                               \
    __builtin_amdgcn_s_barrier(); asm volatile("" ::: "memory"); } while (0)
#define VM(n) asm volatile("s_waitcnt vmcnt(" #n ")" ::: "memory")

    f32x4 acc[8][4];
#pragma unroll
    for (int m = 0; m < 8; ++m)
#pragma unroll
        for (int n = 0; n < 4; ++n)
            acc[m][n] = (f32x4){0.f, 0.f, 0.f, 0.f};

    f16x8 afr[8], bfr0[4], bfr1[4];

    // prologue: tile0 complete + tile1.R0 in flight
    STAGE(0, 0); STAGE(0, 1); STAGE(0, 2); STAGE(0, 3);
    STAGE(1, 0);
    VM(2); SB();

    for (int i = 0; i < 31; ++i) {
        const int t0 = 2 * i;
        // tile t0 (buf0)
        LD_P1(0); STAGE(t0 + 1, 1); SB(); MFMAQ(0, 0, bfr0); LD_BFR1(0); SB();
                  STAGE(t0 + 1, 2); SB(); MFMAQ(0, 1, bfr1); LD_AFRH(0); SB();
                  STAGE(t0 + 1, 3); SB(); MFMAQ(1, 1, bfr1);             SB();
                  STAGE(t0 + 2, 0); SB(); MFMAQ(1, 0, bfr0); VM(2);      SB();
        // tile t0+1 (buf1)
        LD_P1(1); STAGE(t0 + 2, 1); SB(); MFMAQ(0, 0, bfr0); LD_BFR1(1); SB();
                  STAGE(t0 + 2, 2); SB(); MFMAQ(0, 1, bfr1); LD_AFRH(1); SB();
                  STAGE(t0 + 2, 3); SB(); MFMAQ(1, 1, bfr1);             SB();
                  STAGE(t0 + 3, 0); SB(); MFMAQ(1, 0, bfr0); VM(2);      SB();
    }
    // tail: tiles 62 (buf0), 63 (buf1); no stages past 63
    LD_P1(0); STAGE(63, 1); SB(); MFMAQ(0, 0, bfr0); LD_BFR1(0); SB();
              STAGE(63, 2); SB(); MFMAQ(0, 1, bfr1); LD_AFRH(0); SB();
              STAGE(63, 3); SB(); MFMAQ(1, 1, bfr1);             SB();
                            SB(); MFMAQ(1, 0, bfr0); VM(0);      SB();
    LD_P1(1);               SB(); MFMAQ(0, 0, bfr0); LD_BFR1(1); SB();
                            SB(); MFMAQ(0, 1, bfr1); LD_AFRH(1); SB();
                            SB(); MFMAQ(1, 1, bfr1);             SB();
                            SB(); MFMAQ(1, 0, bfr0);             SB();

    // epilogue: ref semantics y=fp16(acc); out=f32(fp16(y + fp16(bias)))
#pragma unroll
    for (int nf = 0; nf < 4; ++nf) {
        const int col = n0 + wn * 64 + nf * 16 + fr;
        const _Float16 bh = (_Float16)bias[col];
#pragma unroll
        for (int mf = 0; mf < 8; ++mf) {
            const int row0 = m0 + wm * 128 + mf * 16 + fk * 4;
#pragma unroll
            for (int r = 0; r < 4; ++r) {
                const _Float16 y = (_Float16)acc[mf][nf][r];
                out[(size_t)(row0 + r) * N_TOT + col] = (float)(_Float16)(y + bh);
            }
        }
    }
#undef STAGE
#undef LD_A1
#undef LD_B1
#undef LD_P1
#undef LD_BFR1
#undef LD_AFRH
#undef MFMAQ
#undef SB
#undef VM
}

// ---------------- fallback (proven correct, slow) ----------------------------
__global__ __launch_bounds__(256)
void qlinf32_kernel(const float* __restrict__ x, const uint32_t* __restrict__ qw,
                    const float* __restrict__ sc, const uint32_t* __restrict__ qz,
                    const float* __restrict__ bias, float* __restrict__ out)
{
    const int idx = blockIdx.x * 256 + threadIdx.x;
    const int n   = idx & (N_TOT - 1);
    const int mb  = (idx >> 12) << 2;
    const float s = sc[n];
    const uint32_t z4 = (qz[n >> 3] >> ((n & 7) * 4)) & 15u;
    const float zoff = (float)(z4 + 1u) * s;
    float acc[4] = {0.f, 0.f, 0.f, 0.f};
    const float* xr = x + (size_t)mb * K_TOT;
    for (int kq = 0; kq < KQ; ++kq) {
        const uint32_t q = qw[(size_t)kq * N_TOT + n];
        f32x4 xa[4][2];
#pragma unroll
        for (int r = 0; r < 4; ++r) {
            xa[r][0] = *(const f32x4*)(xr + r * K_TOT + kq * 8);
            xa[r][1] = *(const f32x4*)(xr + r * K_TOT + kq * 8 + 4);
        }
#pragma unroll
        for (int e = 0; e < 8; ++e) {
            const float w = fmaf((float)((q >> (4 * e)) & 15u), s, -zoff);
#pragma unroll
            for (int r = 0; r < 4; ++r)
                acc[r] = fmaf(xa[r][e >> 2][e & 3], w, acc[r]);
        }
    }
    const _Float16 bh = (_Float16)bias[n];
#pragma unroll
    for (int r = 0; r < 4; ++r) {
        _Float16 y = (_Float16)acc[r];
        out[(size_t)(mb + r) * N_TOT + n] = (float)(_Float16)(y + bh);
    }
}

extern "C" void kernel_launch(void* const* d_in, const int* in_sizes, int n_in,
                              void* d_out, int out_size, void* d_ws, size_t ws_size,
                              hipStream_t stream) {
    int ix = -1, iqw = -1, iqz = -1, isc = -1, ibi = -1;
    for (int i = 0; i < n_in; ++i) {
        const int sz = in_sizes[i];
        if      (sz == 33554432) ix  = i;
        else if (sz == 2097152)  iqw = i;
        else if (sz == 512)      iqz = i;
        else if (sz == 4096)     { if (isc < 0) isc = i; else ibi = i; }
    }
    if (ix < 0)  ix = 0;
    if (iqw < 0) iqw = 1;
    if (isc < 0) isc = 2;
    if (iqz < 0) iqz = 3;
    if (ibi < 0) ibi = 4;

    const float*    xv = (const float*)d_in[ix];
    const uint32_t* qw = (const uint32_t*)d_in[iqw];
    const float*    sc = (const float*)d_in[isc];
    const uint32_t* qz = (const uint32_t*)d_in[iqz];
    const float*    bi = (const float*)d_in[ibi];
    float*         out = (float*)d_out;

    if (ws_size < WS_NEEDED) {
        const int blocks = (M_TOT / 4) * N_TOT / 256;
        hipLaunchKernelGGL(qlinf32_kernel, dim3(blocks), dim3(256), 0, stream,
                           xv, qw, sc, qz, bi, out);
        return;
    }

    _Float16* xh = (_Float16*)d_ws;
    _Float16* wt = (_Float16*)((char*)d_ws + WS_XH_BYTES);

    hipLaunchKernelGGL(cvt_x_kernel, dim3(M_TOT * K_TOT / 8 / 256), dim3(256),
                       0, stream, xv, xh);
    hipLaunchKernelGGL(deq_kernel, dim3(KQ * N_TOT / 256), dim3(256),
                       0, stream, qw, sc, qz, wt);
    hipLaunchKernelGGL(gemm8p_kernel, dim3(NWG), dim3(512), 0, stream,
                       xh, wt, bi, out);
}

// Round 10
// 273.524 us; speedup vs baseline: 1.1410x; 1.0262x over previous
//
#include <hip/hip_runtime.h>
#include <stdint.h>

typedef __attribute__((ext_vector_type(8))) _Float16 f16x8;
typedef __attribute__((ext_vector_type(4))) float f32x4;

#define M_TOT 8192
#define K_TOT 4096
#define N_TOT 4096
#define KQ    (K_TOT / 8)

#define BM 256
#define BN 256
#define BK 64
#define NWG ((M_TOT / BM) * (N_TOT / BN))   /* 32*16 = 512 */

#define WS_XH_BYTES   ((size_t)M_TOT * K_TOT * 2)
#define WS_WT_BYTES   ((size_t)N_TOT * K_TOT * 2)
#define WS_NEEDED     (WS_XH_BYTES + WS_WT_BYTES)

__device__ __forceinline__ void async_load16(const void* g, void* l) {
    __builtin_amdgcn_global_load_lds(
        (const __attribute__((address_space(1))) void*)g,
        (__attribute__((address_space(3))) void*)l, 16, 0, 0);
}

// ---------------- pre-pass 1: x f32 -> fp16 (exact) --------------------------
__global__ __launch_bounds__(256)
void cvt_x_kernel(const float* __restrict__ x, _Float16* __restrict__ xh) {
    const size_t i = (size_t)(blockIdx.x * 256 + threadIdx.x) * 8;
    f32x4 v0 = *(const f32x4*)(x + i);
    f32x4 v1 = *(const f32x4*)(x + i + 4);
    f16x8 h;
#pragma unroll
    for (int e = 0; e < 4; ++e) { h[e] = (_Float16)v0[e]; h[e + 4] = (_Float16)v1[e]; }
    *(f16x8*)(xh + i) = h;
}

// ---------------- pre-pass 2: dequant qw -> W^T fp16 [n][k] ------------------
__global__ __launch_bounds__(256)
void deq_kernel(const uint32_t* __restrict__ qw, const float* __restrict__ sc,
                const uint32_t* __restrict__ qz, _Float16* __restrict__ wt) {
    const int t  = blockIdx.x * 256 + threadIdx.x;
    const int kq = t & (KQ - 1);
    const int n  = t >> 9;
    const float s = sc[n];
    const uint32_t z4 = (qz[n >> 3] >> ((n & 7) * 4)) & 15u;
    const float zoff = (float)(z4 + 1u) * s;
    const uint32_t q = qw[(size_t)kq * N_TOT + n];
    f16x8 w;
#pragma unroll
    for (int e = 0; e < 8; ++e)
        w[e] = (_Float16)fmaf((float)((q >> (4 * e)) & 15u), s, -zoff);
    *(f16x8*)(wt + (size_t)n * K_TOT + kq * 8) = w;
}

// ---------------- main GEMM: 256x256, SINGLE-barrier phases ------------------
// Regions/buf: 0=A rows0-127, 1=A rows128-255, 2=B cols0-127, 3=B cols128-255.
// Phase = [ds_reads; stage; (LGKM0/VM); SB; MFMA]. One barrier per phase:
// a wave done with MFMA flows into the next phase's reads while others are
// still on the matrix pipe -> LDS/matrix overlap across waves.
// Safety invariants:
//  - reads complete before their consuming MFMA (compiler lgkm deps), and
//    P3 adds an explicit lgkmcnt(0) BEFORE its barrier so the only
//    one-barrier-later re-stage (P4 -> same-buf R0) cannot overwrite a
//    pending read. All other stages target regions whose last read
//    completed >=2 barriers earlier (checked per region, both buffers).
//  - VM(2)+SB at P4/P8 drains all 4 regions of tile t+1 before its P1
//    (ledger: leftover 2 + P1's 4 + P2's 2 + P4's 2 = 10 -> drain 8, keep
//    the newest 2 = t+2.R0). t+1.R3 is staged at P2 for a >=2-phase lead.
__global__ __launch_bounds__(512, 2)
void gemm8p_kernel(const _Float16* __restrict__ xh,   // (M,K) fp16
                   const _Float16* __restrict__ wt,   // (N,K) fp16
                   const float* __restrict__ bias,    // (N) f32
                   float* __restrict__ out)           // (M,N) f32
{
    __shared__ __align__(16) _Float16 lds[2 * 4 * 8192];   // 128 KiB

    const int tid  = threadIdx.x;
    const int lane = tid & 63;
    const int wave = tid >> 6;
    const int wm = wave >> 2;          // 0..1  A region / 128-row half
    const int wn = wave & 3;           // 0..3  64-col quarter
    const int fr = lane & 15;
    const int fk = lane >> 4;

    const int bid = blockIdx.x;
    const int swz = (bid & 7) * (NWG / 8) + (bid >> 3);   // bijective, 512%8==0
    const int m0 = (swz >> 4) * BM;
    const int n0 = (swz & 15) * BN;

    const int srow = tid >> 3;
    const int c_g  = (tid & 7) ^ (srow & 7);
    const _Float16* gA[2]; const _Float16* gB[2];
    gA[0] = xh + (size_t)(m0 + srow) * K_TOT + c_g * 8;
    gA[1] = xh + (size_t)(m0 + 128 + srow) * K_TOT + c_g * 8;
    gB[0] = wt + (size_t)(n0 + srow) * K_TOT + c_g * 8;
    gB[1] = wt + (size_t)(n0 + 128 + srow) * K_TOT + c_g * 8;

#define STAGE(tile, r) do {                                                    \
    const _Float16* _s = ((r) < 2 ? gA[(r)] : gB[(r) - 2]) + (size_t)(tile) * BK; \
    _Float16* _d = lds + (((tile) & 1) * 4 + (r)) * 8192 + tid * 8;            \
    async_load16(_s, _d);                                                      \
    async_load16(_s + (size_t)64 * K_TOT, _d + 4096);                          \
} while (0)

#define LD_A1(buf, mh, _mf, _kk) do {                                          \
    const _Float16* _b = lds + ((buf) * 4 + wm) * 8192;                        \
    const int _row = ((mh) * 4 + (_mf)) * 16 + fr;                             \
    const int _cp = (((_kk) << 2) | fk) ^ (_row & 7);                          \
    afr[(_mf) * 2 + (_kk)] = *(const f16x8*)(_b + _row * 64 + _cp * 8);        \
} while (0)

#define LD_B1(buf, nh, _nf, _kk, dst) do {                                     \
    const _Float16* _b = lds + ((buf) * 4 + 2 + (wn >> 1)) * 8192;             \
    const int _row = (wn & 1) * 64 + ((nh) * 2 + (_nf)) * 16 + fr;             \
    const int _cp = (((_kk) << 2) | fk) ^ (_row & 7);                          \
    dst[(_nf) * 2 + (_kk)] = *(const f16x8*)(_b + _row * 64 + _cp * 8);        \
} while (0)

// P1 reads, MFMA-consumption-ordered: b0,b1,a0,a1,b2,b3,a2..a7
#define LD_P1(buf) do {                                                        \
    LD_B1(buf, 0, 0, 0, bfr0); LD_B1(buf, 0, 0, 1, bfr0);                      \
    LD_A1(buf, 0, 0, 0);       LD_A1(buf, 0, 0, 1);                            \
    LD_B1(buf, 0, 1, 0, bfr0); LD_B1(buf, 0, 1, 1, bfr0);                      \
    LD_A1(buf, 0, 1, 0);       LD_A1(buf, 0, 1, 1);                            \
    LD_A1(buf, 0, 2, 0);       LD_A1(buf, 0, 2, 1);                            \
    LD_A1(buf, 0, 3, 0);       LD_A1(buf, 0, 3, 1);                            \
} while (0)

#define LD_BFR1(buf) do {                                                      \
    LD_B1(buf, 1, 0, 0, bfr1); LD_B1(buf, 1, 0, 1, bfr1);                      \
    LD_B1(buf, 1, 1, 0, bfr1); LD_B1(buf, 1, 1, 1, bfr1);                      \
} while (0)

#define LD_AFRH(buf) do {                                                      \
    LD_A1(buf, 1, 0, 0); LD_A1(buf, 1, 0, 1);                                  \
    LD_A1(buf, 1, 1, 0); LD_A1(buf, 1, 1, 1);                                  \
    LD_A1(buf, 1, 2, 0); LD_A1(buf, 1, 2, 1);                                  \
    LD_A1(buf, 1, 3, 0); LD_A1(buf, 1, 3, 1);                                  \
} while (0)

#define MFMAQ(mh, nh, bsrc) do {                                               \
    __builtin_amdgcn_s_setprio(1);                                             \
    _Pragma("unroll") for (int _mf = 0; _mf < 4; ++_mf)                        \
    _Pragma("unroll") for (int _nf = 0; _nf < 2; ++_nf)                        \
    _Pragma("unroll") for (int _kk = 0; _kk < 2; ++_kk)                        \
        acc[(mh) * 4 + _mf][(nh) * 2 + _nf] =                                  \
            __builtin_amdgcn_mfma_f32_16x16x32_f16(                            \
                afr[_mf * 2 + _kk], bsrc[_nf * 2 + _kk],                       \
                acc[(mh) * 4 + _mf][(nh) * 2 + _nf], 0, 0, 0);                 \
    __builtin_amdgcn_s_setprio(0);                                             \
} while (0)

#define SB() do { asm volatile("" ::: "memory");                               \
    __builtin_amdgcn_s_barrier(); asm volatile("" ::: "memory"); } while (0)
#define VM(n)  asm volatile("s_waitcnt vmcnt(" #n ")" ::: "memory")
#define LGKM0  asm volatile("s_waitcnt lgkmcnt(0)" ::: "memory")

    f32x4 acc[8][4];
#pragma unroll
    for (int m = 0; m < 8; ++m)
#pragma unroll
        for (int n = 0; n < 4; ++n)
            acc[m][n] = (f32x4){0.f, 0.f, 0.f, 0.f};

    f16x8 afr[8], bfr0[4], bfr1[4];

    // prologue: tile0 complete + tile1.R0 in flight
    STAGE(0, 0); STAGE(0, 1); STAGE(0, 2); STAGE(0, 3);
    STAGE(1, 0);
    VM(2); SB();

    for (int i = 0; i < 31; ++i) {
        const int t0 = 2 * i;
        // tile t0 (buf0)
        LD_P1(0);   STAGE(t0 + 1, 1); STAGE(t0 + 1, 2); SB(); MFMAQ(0, 0, bfr0);
        LD_BFR1(0); STAGE(t0 + 1, 3);                   SB(); MFMAQ(0, 1, bfr1);
        LD_AFRH(0); LGKM0;                              SB(); MFMAQ(1, 1, bfr1);
                    STAGE(t0 + 2, 0); VM(2);            SB(); MFMAQ(1, 0, bfr0);
        // tile t0+1 (buf1)
        LD_P1(1);   STAGE(t0 + 2, 1); STAGE(t0 + 2, 2); SB(); MFMAQ(0, 0, bfr0);
        LD_BFR1(1); STAGE(t0 + 2, 3);                   SB(); MFMAQ(0, 1, bfr1);
        LD_AFRH(1); LGKM0;                              SB(); MFMAQ(1, 1, bfr1);
                    STAGE(t0 + 3, 0); VM(2);            SB(); MFMAQ(1, 0, bfr0);
    }
    // tail: tiles 62 (buf0), 63 (buf1); no stages past tile 63
    LD_P1(0);   STAGE(63, 1); STAGE(63, 2); SB(); MFMAQ(0, 0, bfr0);
    LD_BFR1(0); STAGE(63, 3);               SB(); MFMAQ(0, 1, bfr1);
    LD_AFRH(0); LGKM0;                      SB(); MFMAQ(1, 1, bfr1);
                VM(0);                      SB(); MFMAQ(1, 0, bfr0);
    LD_P1(1);                               SB(); MFMAQ(0, 0, bfr0);
    LD_BFR1(1);                             SB(); MFMAQ(0, 1, bfr1);
    LD_AFRH(1);                             SB(); MFMAQ(1, 1, bfr1);
                                            SB(); MFMAQ(1, 0, bfr0);

    // epilogue: ref semantics y=fp16(acc); out=f32(fp16(y + fp16(bias)))
#pragma unroll
    for (int nf = 0; nf < 4; ++nf) {
        const int col = n0 + wn * 64 + nf * 16 + fr;
        const _Float16 bh = (_Float16)bias[col];
#pragma unroll
        for (int mf = 0; mf < 8; ++mf) {
            const int row0 = m0 + wm * 128 + mf * 16 + fk * 4;
#pragma unroll
            for (int r = 0; r < 4; ++r) {
                const _Float16 y = (_Float16)acc[mf][nf][r];
                out[(size_t)(row0 + r) * N_TOT + col] = (float)(_Float16)(y + bh);
            }
        }
    }
#undef STAGE
#undef LD_A1
#undef LD_B1
#undef LD_P1
#undef LD_BFR1
#undef LD_AFRH
#undef MFMAQ
#undef SB
#undef VM
#undef LGKM0
}

// ---------------- fallback (proven correct, slow) ----------------------------
__global__ __launch_bounds__(256)
void qlinf32_kernel(const float* __restrict__ x, const uint32_t* __restrict__ qw,
                    const float* __restrict__ sc, const uint32_t* __restrict__ qz,
                    const float* __restrict__ bias, float* __restrict__ out)
{
    const int idx = blockIdx.x * 256 + threadIdx.x;
    const int n   = idx & (N_TOT - 1);
    const int mb  = (idx >> 12) << 2;
    const float s = sc[n];
    const uint32_t z4 = (qz[n >> 3] >> ((n & 7) * 4)) & 15u;
    const float zoff = (float)(z4 + 1u) * s;
    float acc[4] = {0.f, 0.f, 0.f, 0.f};
    const float* xr = x + (size_t)mb * K_TOT;
    for (int kq = 0; kq < KQ; ++kq) {
        const uint32_t q = qw[(size_t)kq * N_TOT + n];
        f32x4 xa[4][2];
#pragma unroll
        for (int r = 0; r < 4; ++r) {
            xa[r][0] = *(const f32x4*)(xr + r * K_TOT + kq * 8);
            xa[r][1] = *(const f32x4*)(xr + r * K_TOT + kq * 8 + 4);
        }
#pragma unroll
        for (int e = 0; e < 8; ++e) {
            const float w = fmaf((float)((q >> (4 * e)) & 15u), s, -zoff);
#pragma unroll
            for (int r = 0; r < 4; ++r)
                acc[r] = fmaf(xa[r][e >> 2][e & 3], w, acc[r]);
        }
    }
    const _Float16 bh = (_Float16)bias[n];
#pragma unroll
    for (int r = 0; r < 4; ++r) {
        _Float16 y = (_Float16)acc[r];
        out[(size_t)(mb + r) * N_TOT + n] = (float)(_Float16)(y + bh);
    }
}

extern "C" void kernel_launch(void* const* d_in, const int* in_sizes, int n_in,
                              void* d_out, int out_size, void* d_ws, size_t ws_size,
                              hipStream_t stream) {
    int ix = -1, iqw = -1, iqz = -1, isc = -1, ibi = -1;
    for (int i = 0; i < n_in; ++i) {
        const int sz = in_sizes[i];
        if      (sz == 33554432) ix  = i;
        else if (sz == 2097152)  iqw = i;
        else if (sz == 512)      iqz = i;
        else if (sz == 4096)     { if (isc < 0) isc = i; else ibi = i; }
    }
    if (ix < 0)  ix = 0;
    if (iqw < 0) iqw = 1;
    if (isc < 0) isc = 2;
    if (iqz < 0) iqz = 3;
    if (ibi < 0) ibi = 4;

    const float*    xv = (const float*)d_in[ix];
    const uint32_t* qw = (const uint32_t*)d_in[iqw];
    const float*    sc = (const float*)d_in[isc];
    const uint32_t* qz = (const uint32_t*)d_in[iqz];
    const float*    bi = (const float*)d_in[ibi];
    float*         out = (float*)d_out;

    if (ws_size < WS_NEEDED) {
        const int blocks = (M_TOT / 4) * N_TOT / 256;
        hipLaunchKernelGGL(qlinf32_kernel, dim3(blocks), dim3(256), 0, stream,
                           xv, qw, sc, qz, bi, out);
        return;
    }

    _Float16* xh = (_Float16*)d_ws;
    _Float16* wt = (_Float16*)((char*)d_ws + WS_XH_BYTES);

    hipLaunchKernelGGL(cvt_x_kernel, dim3(M_TOT * K_TOT / 8 / 256), dim3(256),
                       0, stream, xv, xh);
    hipLaunchKernelGGL(deq_kernel, dim3(KQ * N_TOT / 256), dim3(256),
                       0, stream, qw, sc, qz, wt);
    hipLaunchKernelGGL(gemm8p_kernel, dim3(NWG), dim3(512), 0, stream,
                       xh, wt, bi, out);
}